// Round 8
// baseline (2046.194 us; speedup 1.0000x reference)
//
#include <hip/hip_runtime.h>
#include <math.h>

// LSTM persistent kernel, R23: hybrid of the two verified halves.
//   waves 0-3: byte-exact R15 MFMA path, elements 0..63
//              (16 MFMAs/wave = 256cy matrix/SIMD, verified 4-gate tail)
//   waves 4-7: byte-exact R20 quad-K dot2 path, elements 64..127
//              (4 ds_read_b128/lane, 64 dot2 = 256cy, DPP quad reduce,
//               VGPR-lean -- R20 measured NO latency pathology)
//
// Why this works when R16-R22 didn't: R17 MEASURED the cross-wave overlap
// (261cy matrix || 419cy VALU on one SIMD) -- it lost only to the 16-load
// dot2 layout's ~800cy LDS stalls. R20 MEASURED the fix (quad-K layout,
// VGPR 76, clean) -- it lost only to half-rate fdot2 making a PURE-VALU
// kernel issue-bound (816cy/SIMD). Hybrid halves the dot2 work: per SIMD
// ~470cy VALU || 256cy matrix, both pipes concurrent per m114/R17.
// Register union via R18-verified trick: dot2 weights live inside a[4][4].
//
// Every element computed by ops identical to a verified kernel =>
// absmax must stay exactly 2.4414e-4.
//
// Prediction: dur 1688 -> ~1250-1450us; MfmaUtil ~8-9, VALUBusy ~14-16
// reported; VGPR ~100-120. Falsifier: dur >= 1688 => hybrid axis dead;
// revert to R15 and declare the serialization floor.
constexpr int Hdim = 128;
constexpr int TMAX = 4096;

typedef _Float16 v2h __attribute__((ext_vector_type(2)));
typedef _Float16 v8h __attribute__((ext_vector_type(8)));
typedef float v4f __attribute__((ext_vector_type(4)));
typedef unsigned uint;

#if __has_builtin(__builtin_amdgcn_exp2f)
__device__ __forceinline__ float exp2_fast(float x) {
  return __builtin_amdgcn_exp2f(x);
}
#else
__device__ __forceinline__ float exp2_fast(float x) {
  return __expf(x * 0.6931471805599453f);
}
#endif

__device__ __forceinline__ float rcp_fast(float x) {
  return __builtin_amdgcn_rcpf(x);
}

// f32 <- dot2(f16x2, f16x2) + f32, operands carried as uint (bit-cast only).
__device__ __forceinline__ float dot2u(uint a, uint b, float c) {
#if __has_builtin(__builtin_amdgcn_fdot2)
  return __builtin_amdgcn_fdot2(__builtin_bit_cast(v2h, a),
                                __builtin_bit_cast(v2h, b), c, false);
#else
  const v2h x = __builtin_bit_cast(v2h, a);
  const v2h y = __builtin_bit_cast(v2h, b);
  return fmaf((float)x[0], (float)y[0], fmaf((float)x[1], (float)y[1], c));
#endif
}

__device__ __forceinline__ float sel4(v4f d, int r) {
  const float s01 = (r & 1) ? d.y : d.x;
  const float s23 = (r & 1) ? d.w : d.z;
  return (r & 2) ? s23 : s01;
}

// Quad-lane permute via DPP quad_perm (pure VALU, low latency).
template <int CTRL>
__device__ __forceinline__ float qperm(float v) {
#if __has_builtin(__builtin_amdgcn_update_dpp)
  return __int_as_float(
      __builtin_amdgcn_update_dpp(0, __float_as_int(v), CTRL, 0xF, 0xF, true));
#else
  const int x = (CTRL == 0xB1) ? 1 : (CTRL == 0x4E ? 2 : 3);
  return __shfl_xor(v, x, 64);
#endif
}

// Quad butterfly sum (R20-verified): every lane gets the 4-lane total.
__device__ __forceinline__ float qsum(float v) {
  v += qperm<0xB1>(v);  // xor 1
  v += qperm<0x4E>(v);  // xor 2
  return v;
}

__global__ __launch_bounds__(512, 2) void lstm_r23(
    const float* __restrict__ data, const float* __restrict__ h0,
    const float* __restrict__ c0, const float* __restrict__ W_ih,
    const float* __restrict__ W_hh, const float* __restrict__ b_ih,
    const float* __restrict__ b_hh, const float* __restrict__ W_out,
    const float* __restrict__ b_out, float* __restrict__ out, int T) {
  __shared__ __align__(16) float xs[TMAX];
  __shared__ __align__(16) _Float16 hbuf[2][Hdim];

  const int b = blockIdx.x;
  const int tid = threadIdx.x;
  const int lane = tid & 63;
  const int wv = tid >> 6;
  const bool mrole = (wv < 4);  // waves 0-3: MFMA els 0..63; 4-7: dot2

  // Stage input row (coalesced float4).
  {
    const float4* src = (const float4*)(data + (size_t)b * T);
    float4* dst = (float4*)xs;
    for (int i = tid; i < T / 4; i += 512) dst[i] = src[i];
  }

  constexpr float L2E = 1.44269504088896f;

  // Shared persistent weight storage (R18-verified union): MFMA role's
  // A-frags OR dot2 role's 64 weight-uints.
  v8h a[4][4];
  // MFMA-only state.
  v4f acc_init[4];
  float wihm[4];
  int p = 0, m = 0, r = 0;
  // dot2-only state.
  float bias[4] = {0.f, 0.f, 0.f, 0.f};
  float wihd = 0.f;
  int cq = 0;

  int el;
  if (mrole) {
    // ---- exact R15 init: els 16wv+4p+r, A[m][32c+8p+j] Mk-scaled ----
    p = lane >> 4;
    m = lane & 15;
    r = m & 3;
    el = 16 * wv + 4 * p + r;
#pragma unroll
    for (int g = 0; g < 4; ++g) {
      const int row = 128 * g + 16 * wv + m;
      const float Mr = (g == 2) ? 2.0f * L2E : -L2E;
      const float* wr = W_hh + (size_t)row * Hdim + 8 * p;
#pragma unroll
      for (int c = 0; c < 4; ++c) {
        float4 v0 = ((const float4*)(wr + 32 * c))[0];
        float4 v1 = ((const float4*)(wr + 32 * c))[1];
        a[g][c] = v8h{(_Float16)(Mr * v0.x), (_Float16)(Mr * v0.y),
                      (_Float16)(Mr * v0.z), (_Float16)(Mr * v0.w),
                      (_Float16)(Mr * v1.x), (_Float16)(Mr * v1.y),
                      (_Float16)(Mr * v1.z), (_Float16)(Mr * v1.w)};
      }
    }
#pragma unroll
    for (int g = 0; g < 4; ++g) {
      const float Mr = (g == 2) ? 2.0f * L2E : -L2E;
      const int row = 128 * g + 16 * wv + 4 * p;
      acc_init[g] = v4f{Mr * (b_ih[row + 0] + b_hh[row + 0]),
                        Mr * (b_ih[row + 1] + b_hh[row + 1]),
                        Mr * (b_ih[row + 2] + b_hh[row + 2]),
                        Mr * (b_ih[row + 3] + b_hh[row + 3])};
      wihm[g] = Mr * W_ih[128 * g + el];
    }
  } else {
    // ---- exact R20 init on els 64..127: quad j owns e, lane cq owns
    // K-quarter [32cq,32cq+32) of all 4 gate rows; weights into a[][].
    const int s = wv - 4;
    const int j = lane >> 2;
    cq = lane & 3;
    el = 64 + 16 * s + j;
#pragma unroll
    for (int g = 0; g < 4; ++g) {
      const int row = 128 * g + el;
      const float Mr = (g == 2) ? 2.0f * L2E : -L2E;
      const float* wr = W_hh + (size_t)row * Hdim + 32 * cq;
#pragma unroll
      for (int c = 0; c < 4; ++c) {  // a[g][c] = K [32cq+8c, 32cq+8c+8)
        float4 v0 = ((const float4*)(wr + 8 * c))[0];
        float4 v1 = ((const float4*)(wr + 8 * c))[1];
        a[g][c] = v8h{(_Float16)(Mr * v0.x), (_Float16)(Mr * v0.y),
                      (_Float16)(Mr * v0.z), (_Float16)(Mr * v0.w),
                      (_Float16)(Mr * v1.x), (_Float16)(Mr * v1.y),
                      (_Float16)(Mr * v1.z), (_Float16)(Mr * v1.w)};
      }
      bias[g] = (cq == 0) ? Mr * (b_ih[row] + b_hh[row]) : 0.0f;
    }
    const float Mq = (cq == 2) ? 2.0f * L2E : -L2E;
    wihd = Mq * W_ih[128 * cq + el];
  }

  float cst = c0[(size_t)b * Hdim + el];
  if (tid < 128) hbuf[0][tid] = (_Float16)h0[(size_t)b * Hdim + tid];
  __syncthreads();

  for (int t0 = 0; t0 < T; t0 += 4) {
    const float4 xv = *(const float4*)&xs[t0];  // 4 steps of x, one read
    const float xts[4] = {xv.x, xv.y, xv.z, xv.w};
#pragma unroll
    for (int u = 0; u < 4; ++u) {
      const int t = t0 + u;
      const _Float16* hb = hbuf[t & 1];
      _Float16* hn = hbuf[(t + 1) & 1];
      const float xt = xts[u];

      if (mrole) {
        // ---- exact R15 inner body ----
        v8h bq[4];
#pragma unroll
        for (int c = 0; c < 4; ++c) bq[c] = *(const v8h*)(hb + 32 * c + 8 * p);

        v4f d0 = __builtin_amdgcn_mfma_f32_16x16x32_f16(a[0][0], bq[0],
                                                        acc_init[0], 0, 0, 0);
        v4f d1 = __builtin_amdgcn_mfma_f32_16x16x32_f16(a[1][0], bq[0],
                                                        acc_init[1], 0, 0, 0);
        v4f d2 = __builtin_amdgcn_mfma_f32_16x16x32_f16(a[2][0], bq[0],
                                                        acc_init[2], 0, 0, 0);
        v4f d3 = __builtin_amdgcn_mfma_f32_16x16x32_f16(a[3][0], bq[0],
                                                        acc_init[3], 0, 0, 0);
#pragma unroll
        for (int c = 1; c < 4; ++c) {
          d0 = __builtin_amdgcn_mfma_f32_16x16x32_f16(a[0][c], bq[c], d0, 0, 0, 0);
          d1 = __builtin_amdgcn_mfma_f32_16x16x32_f16(a[1][c], bq[c], d1, 0, 0, 0);
          d2 = __builtin_amdgcn_mfma_f32_16x16x32_f16(a[2][c], bq[c], d2, 0, 0, 0);
          d3 = __builtin_amdgcn_mfma_f32_16x16x32_f16(a[3][c], bq[c], d3, 0, 0, 0);
        }

        const float zi = sel4(d0, r);
        const float zf = sel4(d1, r);
        const float zg = sel4(d2, r);
        const float zo = sel4(d3, r);

        const float yi = rcp_fast(1.0f + exp2_fast(fmaf(xt, wihm[0], zi)));
        const float yf = rcp_fast(1.0f + exp2_fast(fmaf(xt, wihm[1], zf)));
        const float yg = fmaf(
            -2.0f, rcp_fast(1.0f + exp2_fast(fmaf(xt, wihm[2], zg))), 1.0f);
        const float yo = rcp_fast(1.0f + exp2_fast(fmaf(xt, wihm[3], zo)));

        cst = fmaf(yf, cst, yi * yg);
        const float th = fmaf(
            -2.0f, rcp_fast(1.0f + exp2_fast(cst * (2.0f * L2E))), 1.0f);
        const float h = yo * th;
        if (m < 4) hn[el] = (_Float16)h;
      } else {
        // ---- exact R20 inner body (weights read out of a[][]) ----
        const uint4* hp = (const uint4*)hb;
        uint4 hqs[4];
#pragma unroll
        for (int i = 0; i < 4; ++i) hqs[i] = hp[4 * cq + i];

        float A0 = bias[0], A1 = bias[1], A2 = bias[2], A3 = bias[3];
#pragma unroll
        for (int c = 0; c < 4; ++c) {
          const uint4 q0 = __builtin_bit_cast(uint4, a[0][c]);
          const uint4 q1 = __builtin_bit_cast(uint4, a[1][c]);
          const uint4 q2 = __builtin_bit_cast(uint4, a[2][c]);
          const uint4 q3 = __builtin_bit_cast(uint4, a[3][c]);
          const uint4 hh = hqs[c];
          A0 = dot2u(q0.x, hh.x, A0);
          A1 = dot2u(q1.x, hh.x, A1);
          A2 = dot2u(q2.x, hh.x, A2);
          A3 = dot2u(q3.x, hh.x, A3);
          A0 = dot2u(q0.y, hh.y, A0);
          A1 = dot2u(q1.y, hh.y, A1);
          A2 = dot2u(q2.y, hh.y, A2);
          A3 = dot2u(q3.y, hh.y, A3);
          A0 = dot2u(q0.z, hh.z, A0);
          A1 = dot2u(q1.z, hh.z, A1);
          A2 = dot2u(q2.z, hh.z, A2);
          A3 = dot2u(q3.z, hh.z, A3);
          A0 = dot2u(q0.w, hh.w, A0);
          A1 = dot2u(q1.w, hh.w, A1);
          A2 = dot2u(q2.w, hh.w, A2);
          A3 = dot2u(q3.w, hh.w, A3);
        }

        // Quad butterfly: every lane gets all 4 gate totals.
        A0 = qsum(A0);
        A1 = qsum(A1);
        A2 = qsum(A2);
        A3 = qsum(A3);

        // Lane cq computes gate cq's activation only.
        const float zA = (cq & 1) ? A1 : A0;
        const float zB = (cq & 1) ? A3 : A2;
        const float z = (cq & 2) ? zB : zA;
        const float uu = rcp_fast(1.0f + exp2_fast(fmaf(xt, wihd, z)));

        const float x1 = qperm<0xB1>(uu);
        const float x2 = qperm<0x4E>(uu);
        const float x3 = qperm<0x1B>(uu);

        const float yg = fmaf(-2.0f, x2, 1.0f);  // tanh(raw_g) in lane0
        cst = fmaf(x1, cst, uu * yg);            // c = f*c + i*g
        const float th = fmaf(
            -2.0f, rcp_fast(1.0f + exp2_fast(cst * (2.0f * L2E))), 1.0f);
        if (cq == 0) hn[el] = (_Float16)(x3 * th);  // h = o * tanh(c)
      }
      __syncthreads();
    }
  }

  // Final linear: out[b] = h_T . W_out + b_out (wave 0).
  if (tid < 64) {
    const _Float16* hf = hbuf[T & 1];
    float sum =
        (float)hf[tid] * W_out[tid] + (float)hf[tid + 64] * W_out[tid + 64];
#pragma unroll
    for (int off = 32; off > 0; off >>= 1) sum += __shfl_down(sum, off, 64);
    if (tid == 0) out[b] = sum + b_out[0];
  }
}

extern "C" void kernel_launch(void* const* d_in, const int* in_sizes, int n_in,
                              void* d_out, int out_size, void* d_ws,
                              size_t ws_size, hipStream_t stream) {
  const float* data = (const float*)d_in[0];
  const float* h0 = (const float*)d_in[1];
  const float* c0 = (const float*)d_in[2];
  const float* W_ih = (const float*)d_in[3];
  const float* W_hh = (const float*)d_in[4];
  const float* b_ih = (const float*)d_in[5];
  const float* b_hh = (const float*)d_in[6];
  const float* W_out = (const float*)d_in[7];
  const float* b_out = (const float*)d_in[8];
  float* out = (float*)d_out;

  const int B = in_sizes[1] / Hdim;  // 64
  const int T = in_sizes[0] / B;     // 4096

  lstm_r23<<<B, 512, 0, stream>>>(data, h0, c0, W_ih, W_hh, b_ih, b_hh, W_out,
                                  b_out, out, T);
}